// Round 10
// baseline (1185.011 us; speedup 1.0000x reference)
//
#include <hip/hip_runtime.h>
#include <hip/hip_bf16.h>
#include <math.h>

namespace {
constexpr int V = 32000, D = 1024, L = 8, H = 16, T = 128, F = 2816, DH = 64;
constexpr float EPS = 1e-5f;
constexpr float SCALE = 0.125f; // 1/sqrt(DH)
constexpr int QKVN = 3 * D;     // 3072
constexpr int GUN  = 2 * F;     // 5632
constexpr int NP_Q = 4;         // QKV split-K chunks (CH=256)
constexpr int NP_O = 8;         // O-proj chunks (CH=128)
constexpr int NP_G = 4;         // GU chunks (CH=256)
constexpr int NP_D = 11;        // Wd chunks (K=2816 = 11*256)
}

typedef __attribute__((ext_vector_type(8))) short short8;
typedef __attribute__((ext_vector_type(4))) float f32x4;

__device__ __forceinline__ unsigned short f2bf(float x) {
    union { float f; unsigned u; } v; v.f = x;
    unsigned r = v.u + 0x7FFFu + ((v.u >> 16) & 1u);
    return (unsigned short)(r >> 16);
}

// ---------------- Embedding gather + RoPE tables (fused) ----------------
__global__ void embed_rope_kernel(const int* __restrict__ ids, const float* __restrict__ emb,
                                  float* __restrict__ X,
                                  float* __restrict__ cosT, float* __restrict__ sinT) {
    int t = blockIdx.x, tid = threadIdx.x;
    int id = ids[t];
    ((float4*)(X + (size_t)t * D))[tid] = ((const float4*)(emb + (size_t)id * D))[tid];
    if (tid < 32) {
        float inv = powf(10000.0f, -(2.0f * (float)tid) / (float)DH);
        float ang = (float)t * inv;
        cosT[t * 32 + tid] = cosf(ang);
        sinT[t * 32 + tid] = sinf(ang);
    }
}

// ---------------- RMSNorm (X is final; no partials) + fused zero of next buffer ----------------
// Block t: zeroes zb4[t*zcount .. +zcount) (float4 units), then Y[t,:] = norm(X[t,:])*w.
template<bool BF16OUT>
__launch_bounds__(256)
__global__ void rmsnorm_zero_kernel(const float* __restrict__ X, const float* __restrict__ w,
                                    void* __restrict__ Y, float4* __restrict__ zb4, int zcount) {
    int t = blockIdx.x, tid = threadIdx.x;
    if (zb4) {
        float4 z = {0.f, 0.f, 0.f, 0.f};
        float4* zb = zb4 + (size_t)t * zcount;
        for (int i = tid; i < zcount; i += 256) zb[i] = z;
    }
    float4 xv = ((const float4*)(X + (size_t)t * D))[tid];
    float s = xv.x * xv.x + xv.y * xv.y + xv.z * xv.z + xv.w * xv.w;
    for (int o = 32; o >= 1; o >>= 1) s += __shfl_xor(s, o);
    __shared__ float red[4];
    if ((tid & 63) == 0) red[tid >> 6] = s;
    __syncthreads();
    float tot = red[0] + red[1] + red[2] + red[3];
    float r = rsqrtf(tot / (float)D + EPS);
    float4 wv = ((const float4*)w)[tid];
    if (BF16OUT) {
        ushort4 y;
        y.x = f2bf(xv.x * r * wv.x); y.y = f2bf(xv.y * r * wv.y);
        y.z = f2bf(xv.z * r * wv.z); y.w = f2bf(xv.w * r * wv.w);
        ((ushort4*)((unsigned short*)Y + (size_t)t * D))[tid] = y;
    } else {
        float4 y;
        y.x = xv.x * r * wv.x; y.y = xv.y * r * wv.y;
        y.z = xv.z * r * wv.z; y.w = xv.w * r * wv.w;
        ((float4*)((float*)Y + (size_t)t * D))[tid] = y;
    }
}

// ---------------- 64-col staged MFMA GEMM, split-K, fp32 ATOMIC accumulate ----------------
// Block: 64 cols (blockIdx.x), K-chunk CH (blockIdx.y), W0/W1/W2 via blockIdx.z.
// Accumulates directly into out (final buffer, col += zColOff*z) with HW f32 atomics.
template<int CH>
__launch_bounds__(256)
__global__ void gemm64_kernel(const unsigned short* __restrict__ A, int lda,
                              const float* __restrict__ W0, const float* __restrict__ W1,
                              const float* __restrict__ W2, int ldw,
                              float* __restrict__ out, int ldo, int zColOff) {
    constexpr int STAGES = CH / 128;
    constexpr int LSTR = 136;
    __shared__ unsigned short Bst[2][64 * LSTR];
    const float* W = blockIdx.z == 0 ? W0 : (blockIdx.z == 1 ? W1 : W2);
    const int tid = threadIdx.x;
    const int wave = tid >> 6, lane = tid & 63;
    const int n0 = blockIdx.x * 64;
    const int k0 = blockIdx.y * CH;
    const int sc = tid & 63;
    const int so = tid >> 6;
    const float* wCol = W + (size_t)k0 * ldw + n0 + sc;
    unsigned short* wp = &Bst[0][sc * LSTR];
    const int lrow = lane & 15;
    const int lqo = lane >> 4;
    const unsigned short* aB = A + (size_t)lrow * lda + k0 + lqo * 8;
    const unsigned short* bRd = &Bst[0][(wave * 16 + lrow) * LSTR + lqo * 8];
    f32x4 acc[8] = {};
    float pre[32];
    auto ldst = [&](int s) {
        #pragma unroll
        for (int p = 0; p < 4; ++p) {
            const float* src = wCol + (size_t)(s * 128 + (so * 4 + p) * 8) * ldw;
            #pragma unroll
            for (int j = 0; j < 8; ++j) pre[p * 8 + j] = src[(size_t)j * ldw];
        }
    };
    auto wrst = [&](int buf) {
        #pragma unroll
        for (int p = 0; p < 4; ++p) {
            short8 bv;
            #pragma unroll
            for (int j = 0; j < 8; ++j) bv[j] = (short)f2bf(pre[p * 8 + j]);
            *(short8*)(wp + buf * (64 * LSTR) + (so * 4 + p) * 8) = bv;
        }
    };
    ldst(0);
    wrst(0);
    __syncthreads();
    #pragma unroll
    for (int s = 0; s < STAGES; ++s) {
        if (s + 1 < STAGES) ldst(s + 1);
        const unsigned short* rd = bRd + (s & 1) * (64 * LSTR);
        #pragma unroll
        for (int ks = 0; ks < 4; ++ks) {
            short8 b = *(const short8*)(rd + ks * 32);
            #pragma unroll
            for (int mf = 0; mf < 8; ++mf) {
                short8 a = *(const short8*)(aB + (size_t)(mf * 16) * lda + s * 128 + ks * 32);
                acc[mf] = __builtin_amdgcn_mfma_f32_16x16x32_bf16(a, b, acc[mf], 0, 0, 0);
            }
        }
        if (s + 1 < STAGES) {
            __syncthreads();
            wrst((s + 1) & 1);
            __syncthreads();
        }
    }
    const int col = zColOff * blockIdx.z + n0 + wave * 16 + lrow;
    #pragma unroll
    for (int mf = 0; mf < 8; ++mf) {
        int r0 = mf * 16 + lqo * 4;
        #pragma unroll
        for (int r = 0; r < 4; ++r)
            unsafeAtomicAdd(&out[(size_t)(r0 + r) * ldo + col], acc[mf][r]);
    }
}

// ---------------- Attention with inline RoPE; QKV [T][3072] fp32 final values ----------------
// 4 heads/block (wave-private LDS, no __syncthreads), fixed-trip unrolled PV.
__launch_bounds__(256)
__global__ void attn_rope_kernel(const float* __restrict__ QKV,
                                 const float* __restrict__ cosT, const float* __restrict__ sinT,
                                 unsigned short* __restrict__ AO) {
    int t = blockIdx.x;
    int wave = threadIdx.x >> 6, lane = threadIdx.x & 63;
    int h = blockIdx.y * 4 + wave;
    __shared__ float qs[4][64];
    __shared__ float ps[4][128];
    float* q = qs[wave];
    float* p = ps[wave];
    // roped Q for this (t,h)
    float qv = QKV[(size_t)t * QKVN + h * DH + lane];
    float qpart = __shfl_xor(qv, 32);
    {
        int i = lane & 31;
        float c = cosT[t * 32 + i], sn = sinT[t * 32 + i];
        q[lane] = (lane < 32) ? (qv * c - qpart * sn) : (qv * c + qpart * sn);
    }
    // scores with inline K-rope (computed unconditionally, masked after)
    int j0 = lane, j1 = lane + 64;
    const float* kr0 = QKV + (size_t)j0 * QKVN + D + h * DH;
    const float* kr1 = QKV + (size_t)j1 * QKVN + D + h * DH;
    const float* cr0 = cosT + j0 * 32;
    const float* sr0 = sinT + j0 * 32;
    const float* cr1 = cosT + j1 * 32;
    const float* sr1 = sinT + j1 * 32;
    float s0 = 0.f, s1 = 0.f;
    #pragma unroll 8
    for (int d = 0; d < 32; ++d) {
        float ka0 = kr0[d], kb0 = kr0[d + 32];
        float c0 = cr0[d], sn0 = sr0[d];
        s0 += q[d] * (ka0 * c0 - kb0 * sn0) + q[d + 32] * (kb0 * c0 + ka0 * sn0);
        float ka1 = kr1[d], kb1 = kr1[d + 32];
        float c1 = cr1[d], sn1 = sr1[d];
        s1 += q[d] * (ka1 * c1 - kb1 * sn1) + q[d + 32] * (kb1 * c1 + ka1 * sn1);
    }
    s0 = (j0 <= t) ? s0 * SCALE : -1e30f;
    s1 = (j1 <= t) ? s1 * SCALE : -1e30f;
    float m = fmaxf(s0, s1);
    for (int o = 32; o >= 1; o >>= 1) m = fmaxf(m, __shfl_xor(m, o));
    float e0 = (j0 <= t) ? __expf(s0 - m) : 0.f;
    float e1 = (j1 <= t) ? __expf(s1 - m) : 0.f;
    float sum = e0 + e1;
    for (int o = 32; o >= 1; o >>= 1) sum += __shfl_xor(sum, o);
    float inv = 1.f / sum;
    p[j0] = e0 * inv;   // p[j] = 0 for j > t  -> fixed-trip PV below is exact
    p[j1] = e1 * inv;
    // PV: fixed 128 trips, unrolled, 4 independent accumulator chains
    const float* vcol = QKV + 2 * D + h * DH + lane;
    float a0 = 0.f, a1 = 0.f, a2 = 0.f, a3 = 0.f;
    #pragma unroll
    for (int j = 0; j < T; j += 4) {
        a0 = fmaf(p[j],     vcol[(size_t)(j)     * QKVN], a0);
        a1 = fmaf(p[j + 1], vcol[(size_t)(j + 1) * QKVN], a1);
        a2 = fmaf(p[j + 2], vcol[(size_t)(j + 2) * QKVN], a2);
        a3 = fmaf(p[j + 3], vcol[(size_t)(j + 3) * QKVN], a3);
    }
    AO[(size_t)t * D + h * DH + lane] = f2bf((a0 + a1) + (a2 + a3));
}

// ---------------- silu(g)*u from final GU fp32 -> Gact bf16 [T][F] ----------------
__launch_bounds__(256)
__global__ void silu_kernel(const float* __restrict__ GU, unsigned short* __restrict__ Gact) {
    int t = blockIdx.y;
    int f = blockIdx.x * 256 + threadIdx.x;
    float g = GU[(size_t)t * GUN + f];
    float u = GU[(size_t)t * GUN + F + f];
    Gact[(size_t)t * F + f] = f2bf(g / (1.f + __expf(-g)) * u);
}

// ---------------- logits: out[v] = emb[v,:] . xl ----------------
__global__ void logits_kernel(const float* __restrict__ emb, const float* __restrict__ xl,
                              float* __restrict__ out) {
    __shared__ float x[D];
    int tid = threadIdx.x;
    ((float4*)x)[tid] = ((const float4*)xl)[tid];
    __syncthreads();
    int row = blockIdx.x * 4 + (tid >> 6);
    int lane = tid & 63;
    const float4* e4 = (const float4*)(emb + (size_t)row * D);
    const float4* x4 = (const float4*)x;
    float s = 0.f;
    #pragma unroll
    for (int k = lane; k < D / 4; k += 64) {
        float4 ev = e4[k], xv = x4[k];
        s += ev.x * xv.x + ev.y * xv.y + ev.z * xv.z + ev.w * xv.w;
    }
    for (int o = 32; o >= 1; o >>= 1) s += __shfl_xor(s, o);
    if (lane == 0) out[row] = s;
}

extern "C" void kernel_launch(void* const* d_in, const int* in_sizes, int n_in,
                              void* d_out, int out_size, void* d_ws, size_t ws_size,
                              hipStream_t stream) {
    const int*   ids = (const int*)d_in[0];
    const float* emb = (const float*)d_in[1];
    const float* Wq  = (const float*)d_in[2];
    const float* Wk  = (const float*)d_in[3];
    const float* Wv  = (const float*)d_in[4];
    const float* Wo  = (const float*)d_in[5];
    const float* Wg  = (const float*)d_in[6];
    const float* Wu  = (const float*)d_in[7];
    const float* Wd  = (const float*)d_in[8];
    const float* attn_norm = (const float*)d_in[9];
    const float* ffn_norm  = (const float*)d_in[10];
    const float* norm_out  = (const float*)d_in[11];
    float* out = (float*)d_out;

    size_t off = 0;
    auto alloc = [&](size_t bytes) {
        void* p = (char*)d_ws + off;
        off += (bytes + 255) & ~(size_t)255;
        return p;
    };
    float*          X     = (float*)alloc((size_t)T * D * 4);
    float*          QKV   = (float*)alloc((size_t)T * QKVN * 4);
    float*          GU    = (float*)alloc((size_t)T * GUN * 4);
    float*          cosT  = (float*)alloc((size_t)T * 32 * 4);
    float*          sinT  = (float*)alloc((size_t)T * 32 * 4);
    float*          xl    = (float*)alloc((size_t)D * 4);
    unsigned short* Hn_bf = (unsigned short*)alloc((size_t)T * D * 2);
    unsigned short* AO_bf = (unsigned short*)alloc((size_t)T * D * 2);
    unsigned short* Gact  = (unsigned short*)alloc((size_t)T * F * 2);
    (void)ws_size;

    embed_rope_kernel<<<T, 256, 0, stream>>>(ids, emb, X, cosT, sinT);

    for (int l = 0; l < L; ++l) {
        const float* wq = Wq + (size_t)l * D * D;
        const float* wk = Wk + (size_t)l * D * D;
        const float* wv = Wv + (size_t)l * D * D;
        const float* wo = Wo + (size_t)l * D * D;
        const float* wg = Wg + (size_t)l * D * F;
        const float* wu = Wu + (size_t)l * D * F;
        const float* wd = Wd + (size_t)l * F * D;

        // Hn = rmsnorm(X)*attn_norm (bf16); zero QKV for atomic accumulation
        rmsnorm_zero_kernel<true><<<T, 256, 0, stream>>>(
            X, attn_norm + (size_t)l * D, Hn_bf, (float4*)QKV, QKVN / 4);
        // QKV: 64-col, K=1024 split 4x256, z in {q,k,v} -> 192 blocks, atomic into QKV
        gemm64_kernel<256><<<dim3(D / 64, NP_Q, 3), 256, 0, stream>>>(
            Hn_bf, D, wq, wk, wv, D, QKV, QKVN, D);
        // attention with inline RoPE -> AO bf16 (512 blocks)
        attn_rope_kernel<<<dim3(T, H / 4), 256, 0, stream>>>(QKV, cosT, sinT, AO_bf);
        // O-proj: K=1024 split 8x128 -> 128 blocks, atomic residual-add onto X
        gemm64_kernel<128><<<dim3(D / 64, NP_O, 1), 256, 0, stream>>>(
            AO_bf, D, wo, wo, wo, D, X, D, 0);
        // Hn = rmsnorm(X)*ffn_norm; zero GU
        rmsnorm_zero_kernel<true><<<T, 256, 0, stream>>>(
            X, ffn_norm + (size_t)l * D, Hn_bf, (float4*)GU, GUN / 4);
        // G,U: K=1024 split 4x256, z in {g,u} -> 352 blocks, atomic into GU
        gemm64_kernel<256><<<dim3(F / 64, NP_G, 2), 256, 0, stream>>>(
            Hn_bf, D, wg, wu, wu, F, GU, GUN, F);
        // silu(g)*u -> Gact bf16
        silu_kernel<<<dim3(F / 256, T), 256, 0, stream>>>(GU, Gact);
        // Wd: K=2816 split 11x256 -> 176 blocks, atomic residual-add onto X
        gemm64_kernel<256><<<dim3(D / 64, NP_D, 1), 256, 0, stream>>>(
            Gact, F, wd, wd, wd, D, X, D, 0);
    }

    // final: xl = rmsnorm(X[127]) * norm_out (fp32; X already final)
    rmsnorm_zero_kernel<false><<<1, 256, 0, stream>>>(
        X + (size_t)(T - 1) * D, norm_out, xl, nullptr, 0);
    logits_kernel<<<V / 4, 256, 0, stream>>>(emb, xl, out);
}

// Round 11
// 707.936 us; speedup vs baseline: 1.6739x; 1.6739x over previous
//
#include <hip/hip_runtime.h>
#include <hip/hip_bf16.h>
#include <math.h>

namespace {
constexpr int V = 32000, D = 1024, L = 8, H = 16, T = 128, F = 2816, DH = 64;
constexpr float EPS = 1e-5f;
constexpr float SCALE = 0.125f; // 1/sqrt(DH)
constexpr int QKVN = 3 * D;     // 3072
constexpr int GUN  = 2 * F;     // 5632
constexpr int NP_Q = 4;         // QKV split-K chunks (CH=256)
constexpr int NP_O = 8;         // O-proj chunks (CH=128)
constexpr int NP_G = 4;         // GU chunks (CH=256)
constexpr int NP_D = 11;        // Wd chunks (K=2816 = 11*256)
}

typedef __attribute__((ext_vector_type(8))) short short8;
typedef __attribute__((ext_vector_type(4))) float f32x4;

__device__ __forceinline__ unsigned short f2bf(float x) {
    union { float f; unsigned u; } v; v.f = x;
    unsigned r = v.u + 0x7FFFu + ((v.u >> 16) & 1u);
    return (unsigned short)(r >> 16);
}

// ---------------- Embedding gather + RoPE tables (fused) ----------------
__global__ void embed_rope_kernel(const int* __restrict__ ids, const float* __restrict__ emb,
                                  float* __restrict__ X,
                                  float* __restrict__ cosT, float* __restrict__ sinT) {
    int t = blockIdx.x, tid = threadIdx.x;
    int id = ids[t];
    ((float4*)(X + (size_t)t * D))[tid] = ((const float4*)(emb + (size_t)id * D))[tid];
    if (tid < 32) {
        float inv = powf(10000.0f, -(2.0f * (float)tid) / (float)DH);
        float ang = (float)t * inv;
        cosT[t * 32 + tid] = cosf(ang);
        sinT[t * 32 + tid] = sinf(ang);
    }
}

// ---------------- RMSNorm + unrolled partial-sum residual update ----------------
template<int NP, bool BF16OUT>
__launch_bounds__(256)
__global__ void rmsnorm_sum_kernel(float* __restrict__ X, const float* __restrict__ P,
                                   const float* __restrict__ w, void* __restrict__ Y) {
    int t = blockIdx.x, tid = threadIdx.x;
    float4 xv = ((float4*)(X + (size_t)t * D))[tid];
    #pragma unroll
    for (int c = 0; c < NP; ++c) {
        float4 pv = ((const float4*)(P + ((size_t)c * T + t) * D))[tid];
        xv.x += pv.x; xv.y += pv.y; xv.z += pv.z; xv.w += pv.w;
    }
    if (NP) ((float4*)(X + (size_t)t * D))[tid] = xv;
    float s = xv.x * xv.x + xv.y * xv.y + xv.z * xv.z + xv.w * xv.w;
    for (int o = 32; o >= 1; o >>= 1) s += __shfl_xor(s, o);
    __shared__ float red[4];
    if ((tid & 63) == 0) red[tid >> 6] = s;
    __syncthreads();
    float tot = red[0] + red[1] + red[2] + red[3];
    float r = rsqrtf(tot / (float)D + EPS);
    float4 wv = ((const float4*)w)[tid];
    if (BF16OUT) {
        ushort4 y;
        y.x = f2bf(xv.x * r * wv.x); y.y = f2bf(xv.y * r * wv.y);
        y.z = f2bf(xv.z * r * wv.z); y.w = f2bf(xv.w * r * wv.w);
        ((ushort4*)((unsigned short*)Y + (size_t)t * D))[tid] = y;
    } else {
        float4 y;
        y.x = xv.x * r * wv.x; y.y = xv.y * r * wv.y;
        y.z = xv.z * r * wv.z; y.w = xv.w * r * wv.w;
        ((float4*)((float*)Y + (size_t)t * D))[tid] = y;
    }
}

// ---------------- 64-col staged MFMA GEMM, fp32 [K][N] weights, split-K ----------------
// 512 threads / 8 waves: wave = (M-half mh = w>>2) x (col-group cg = w&3).
// Each wave: 16 cols x 64 rows (4 frags). Weight tile staged fp32->bf16 via LDS
// (256B-coalesced), register-prefetched double buffer. Partial stores.
template<int CH>
__launch_bounds__(512)
__global__ void gemm64_kernel(const unsigned short* __restrict__ A, int lda,
                              const float* __restrict__ W0, const float* __restrict__ W1,
                              const float* __restrict__ W2, int ldw,
                              float* __restrict__ out, int ldo, int zColOff,
                              size_t chunkStride) {
    constexpr int STAGES = CH / 128;
    constexpr int LSTR = 136;
    __shared__ unsigned short Bst[2][64 * LSTR];
    const float* W = blockIdx.z == 0 ? W0 : (blockIdx.z == 1 ? W1 : W2);
    const int tid = threadIdx.x;
    const int wave = tid >> 6, lane = tid & 63;
    const int cg = wave & 3, mh = wave >> 2;
    const int n0 = blockIdx.x * 64;
    const int k0 = blockIdx.y * CH;
    // staging: 512 threads, col sc, 2 octets (so*2+p) each
    const int sc = tid & 63;
    const int so = tid >> 6;  // 0..7
    const float* wCol = W + (size_t)k0 * ldw + n0 + sc;
    unsigned short* wp = &Bst[0][sc * LSTR];
    const int lrow = lane & 15;
    const int lqo = lane >> 4;
    const unsigned short* aB = A + (size_t)(mh * 64 + lrow) * lda + k0 + lqo * 8;
    const unsigned short* bRd = &Bst[0][(cg * 16 + lrow) * LSTR + lqo * 8];
    f32x4 acc[4] = {};
    float pre[16];
    auto ldst = [&](int s) {
        #pragma unroll
        for (int p = 0; p < 2; ++p) {
            const float* src = wCol + (size_t)(s * 128 + (so * 2 + p) * 8) * ldw;
            #pragma unroll
            for (int j = 0; j < 8; ++j) pre[p * 8 + j] = src[(size_t)j * ldw];
        }
    };
    auto wrst = [&](int buf) {
        #pragma unroll
        for (int p = 0; p < 2; ++p) {
            short8 bv;
            #pragma unroll
            for (int j = 0; j < 8; ++j) bv[j] = (short)f2bf(pre[p * 8 + j]);
            *(short8*)(wp + buf * (64 * LSTR) + (so * 2 + p) * 8) = bv;
        }
    };
    ldst(0);
    wrst(0);
    __syncthreads();
    #pragma unroll
    for (int s = 0; s < STAGES; ++s) {
        if (s + 1 < STAGES) ldst(s + 1);
        const unsigned short* rd = bRd + (s & 1) * (64 * LSTR);
        #pragma unroll
        for (int ks = 0; ks < 4; ++ks) {
            short8 b = *(const short8*)(rd + ks * 32);
            #pragma unroll
            for (int mf = 0; mf < 4; ++mf) {
                short8 a = *(const short8*)(aB + (size_t)(mf * 16) * lda + s * 128 + ks * 32);
                acc[mf] = __builtin_amdgcn_mfma_f32_16x16x32_bf16(a, b, acc[mf], 0, 0, 0);
            }
        }
        if (s + 1 < STAGES) {
            __syncthreads();
            wrst((s + 1) & 1);
            __syncthreads();
        }
    }
    const int col = zColOff * blockIdx.z + n0 + cg * 16 + lrow;
    float* op = out + blockIdx.y * chunkStride;
    #pragma unroll
    for (int mf = 0; mf < 4; ++mf) {
        int r0 = mh * 64 + mf * 16 + lqo * 4;
        #pragma unroll
        for (int r = 0; r < 4; ++r)
            op[(size_t)(r0 + r) * ldo + col] = acc[mf][r];
    }
}

// ---------------- QKV partial reduce + RoPE -> compact Q,K,V [T][D] fp32 ----------------
__launch_bounds__(256)
__global__ void rope_reduce_kernel(const float* __restrict__ P,
                                   const float* __restrict__ cosT, const float* __restrict__ sinT,
                                   float* __restrict__ Qr, float* __restrict__ Kr,
                                   float* __restrict__ Vr) {
    int t = blockIdx.x, tid = threadIdx.x;
    int d0 = tid * 4;
    float4 q = {0.f, 0.f, 0.f, 0.f}, k = q, v = q;
    #pragma unroll
    for (int c = 0; c < NP_Q; ++c) {
        const float* base = P + ((size_t)c * T + t) * QKVN;
        float4 a = ((const float4*)base)[tid];
        float4 b = ((const float4*)(base + D))[tid];
        float4 w = ((const float4*)(base + 2 * D))[tid];
        q.x += a.x; q.y += a.y; q.z += a.z; q.w += a.w;
        k.x += b.x; k.y += b.y; k.z += b.z; k.w += b.w;
        v.x += w.x; v.y += w.y; v.z += w.z; v.w += w.w;
    }
    float4 c4 = *(const float4*)(cosT + t * 32 + (d0 & 31));
    float4 s4 = *(const float4*)(sinT + t * 32 + (d0 & 31));
    float sgn = (d0 & 32) ? 1.f : -1.f;
    float4 qp, kp;
    qp.x = __shfl_xor(q.x, 8); qp.y = __shfl_xor(q.y, 8);
    qp.z = __shfl_xor(q.z, 8); qp.w = __shfl_xor(q.w, 8);
    kp.x = __shfl_xor(k.x, 8); kp.y = __shfl_xor(k.y, 8);
    kp.z = __shfl_xor(k.z, 8); kp.w = __shfl_xor(k.w, 8);
    float4 qo, ko;
    qo.x = q.x * c4.x + sgn * qp.x * s4.x; qo.y = q.y * c4.y + sgn * qp.y * s4.y;
    qo.z = q.z * c4.z + sgn * qp.z * s4.z; qo.w = q.w * c4.w + sgn * qp.w * s4.w;
    ko.x = k.x * c4.x + sgn * kp.x * s4.x; ko.y = k.y * c4.y + sgn * kp.y * s4.y;
    ko.z = k.z * c4.z + sgn * kp.z * s4.z; ko.w = k.w * c4.w + sgn * kp.w * s4.w;
    *(float4*)(Qr + (size_t)t * D + d0) = qo;
    *(float4*)(Kr + (size_t)t * D + d0) = ko;
    *(float4*)(Vr + (size_t)t * D + d0) = v;
}

// ---------------- Causal attention: 4 heads/block, fixed-trip unrolled PV ----------------
__launch_bounds__(256)
__global__ void attn_kernel(const float* __restrict__ Q, const float* __restrict__ Kc,
                            const float* __restrict__ Vc, unsigned short* __restrict__ AO) {
    int t = blockIdx.x;
    int wave = threadIdx.x >> 6, lane = threadIdx.x & 63;
    int h = blockIdx.y * 4 + wave;
    __shared__ float qs[4][64];
    __shared__ float ps[4][128];
    float* q = qs[wave];
    float* p = ps[wave];
    q[lane] = Q[(size_t)t * D + h * DH + lane];
    __syncthreads();
    int j0 = lane, j1 = lane + 64;
    const float* kr0 = Kc + (size_t)j0 * D + h * DH;
    const float* kr1 = Kc + (size_t)j1 * D + h * DH;
    float s0 = 0.f, s1 = 0.f;
    #pragma unroll
    for (int d = 0; d < DH; ++d) {
        float qd = q[d];
        s0 = fmaf(qd, kr0[d], s0);
        s1 = fmaf(qd, kr1[d], s1);
    }
    s0 = (j0 <= t) ? s0 * SCALE : -1e30f;
    s1 = (j1 <= t) ? s1 * SCALE : -1e30f;
    float m = fmaxf(s0, s1);
    for (int o = 32; o >= 1; o >>= 1) m = fmaxf(m, __shfl_xor(m, o));
    float e0 = (j0 <= t) ? __expf(s0 - m) : 0.f;
    float e1 = (j1 <= t) ? __expf(s1 - m) : 0.f;
    float sum = e0 + e1;
    for (int o = 32; o >= 1; o >>= 1) sum += __shfl_xor(sum, o);
    float inv = 1.f / sum;
    p[j0] = e0 * inv;   // p[j] = 0 for j > t  -> fixed-trip PV below is exact
    p[j1] = e1 * inv;
    __syncthreads();
    const float* vcol = Vc + h * DH + lane;
    float a0 = 0.f, a1 = 0.f, a2 = 0.f, a3 = 0.f;
    #pragma unroll
    for (int j = 0; j < T; j += 4) {
        a0 = fmaf(p[j],     vcol[(size_t)(j)     * D], a0);
        a1 = fmaf(p[j + 1], vcol[(size_t)(j + 1) * D], a1);
        a2 = fmaf(p[j + 2], vcol[(size_t)(j + 2) * D], a2);
        a3 = fmaf(p[j + 3], vcol[(size_t)(j + 3) * D], a3);
    }
    AO[(size_t)t * D + h * DH + lane] = f2bf((a0 + a1) + (a2 + a3));
}

// ---------------- GU partial reduce + silu(g)*u -> Gact bf16 [T][F] ----------------
__launch_bounds__(256)
__global__ void silu_reduce_kernel(const float* __restrict__ P,
                                   unsigned short* __restrict__ Gact) {
    int t = blockIdx.y;
    int f = blockIdx.x * 256 + threadIdx.x;
    float g = 0.f, u = 0.f;
    #pragma unroll
    for (int c = 0; c < NP_G; ++c) {
        const float* base = P + ((size_t)c * T + t) * GUN;
        g += base[f];
        u += base[F + f];
    }
    Gact[(size_t)t * F + f] = f2bf(g / (1.f + __expf(-g)) * u);
}

// ---------------- logits: out[v] = emb[v,:] . xl ----------------
__global__ void logits_kernel(const float* __restrict__ emb, const float* __restrict__ xl,
                              float* __restrict__ out) {
    __shared__ float x[D];
    int tid = threadIdx.x;
    ((float4*)x)[tid] = ((const float4*)xl)[tid];
    __syncthreads();
    int row = blockIdx.x * 4 + (tid >> 6);
    int lane = tid & 63;
    const float4* e4 = (const float4*)(emb + (size_t)row * D);
    const float4* x4 = (const float4*)x;
    float s = 0.f;
    #pragma unroll
    for (int k = lane; k < D / 4; k += 64) {
        float4 ev = e4[k], xv = x4[k];
        s += ev.x * xv.x + ev.y * xv.y + ev.z * xv.z + ev.w * xv.w;
    }
    for (int o = 32; o >= 1; o >>= 1) s += __shfl_xor(s, o);
    if (lane == 0) out[row] = s;
}

extern "C" void kernel_launch(void* const* d_in, const int* in_sizes, int n_in,
                              void* d_out, int out_size, void* d_ws, size_t ws_size,
                              hipStream_t stream) {
    const int*   ids = (const int*)d_in[0];
    const float* emb = (const float*)d_in[1];
    const float* Wq  = (const float*)d_in[2];
    const float* Wk  = (const float*)d_in[3];
    const float* Wv  = (const float*)d_in[4];
    const float* Wo  = (const float*)d_in[5];
    const float* Wg  = (const float*)d_in[6];
    const float* Wu  = (const float*)d_in[7];
    const float* Wd  = (const float*)d_in[8];
    const float* attn_norm = (const float*)d_in[9];
    const float* ffn_norm  = (const float*)d_in[10];
    const float* norm_out  = (const float*)d_in[11];
    float* out = (float*)d_out;

    size_t off = 0;
    auto alloc = [&](size_t bytes) {
        void* p = (char*)d_ws + off;
        off += (bytes + 255) & ~(size_t)255;
        return p;
    };
    float*          X     = (float*)alloc((size_t)T * D * 4);
    float*          P0    = (float*)alloc((size_t)NP_Q * T * QKVN * 4);  // QKV partials
    float*          P1    = (float*)alloc((size_t)NP_O * T * D * 4);     // O-proj partials
    float*          P2    = (float*)alloc((size_t)NP_D * T * D * 4);     // Wd partials
    float*          P3    = (float*)alloc((size_t)NP_G * T * GUN * 4);   // GU partials
    float*          Qr    = (float*)alloc((size_t)T * D * 4);
    float*          Kr    = (float*)alloc((size_t)T * D * 4);
    float*          Vr    = (float*)alloc((size_t)T * D * 4);
    float*          cosT  = (float*)alloc((size_t)T * 32 * 4);
    float*          sinT  = (float*)alloc((size_t)T * 32 * 4);
    float*          xl    = (float*)alloc((size_t)D * 4);
    unsigned short* Hn_bf = (unsigned short*)alloc((size_t)T * D * 2);
    unsigned short* AO_bf = (unsigned short*)alloc((size_t)T * D * 2);
    unsigned short* Gact  = (unsigned short*)alloc((size_t)T * F * 2);
    (void)ws_size;

    embed_rope_kernel<<<T, 256, 0, stream>>>(ids, emb, X, cosT, sinT);

    for (int l = 0; l < L; ++l) {
        const float* wq = Wq + (size_t)l * D * D;
        const float* wk = Wk + (size_t)l * D * D;
        const float* wv = Wv + (size_t)l * D * D;
        const float* wo = Wo + (size_t)l * D * D;
        const float* wg = Wg + (size_t)l * D * F;
        const float* wu = Wu + (size_t)l * D * F;
        const float* wd = Wd + (size_t)l * F * D;

        // X += prev Wd partials; Hn = rmsnorm(X)*attn_norm (bf16)
        if (l == 0)
            rmsnorm_sum_kernel<0, true><<<T, 256, 0, stream>>>(
                X, P2, attn_norm + (size_t)l * D, Hn_bf);
        else
            rmsnorm_sum_kernel<NP_D, true><<<T, 256, 0, stream>>>(
                X, P2, attn_norm + (size_t)l * D, Hn_bf);
        // QKV partials: 64-col, K=1024 split 4x256, z in {q,k,v} -> 192 blocks x 8 waves
        gemm64_kernel<256><<<dim3(D / 64, NP_Q, 3), 512, 0, stream>>>(
            Hn_bf, D, wq, wk, wv, D, P0, QKVN, D, (size_t)T * QKVN);
        rope_reduce_kernel<<<T, 256, 0, stream>>>(P0, cosT, sinT, Qr, Kr, Vr);
        // attention: 4 heads/block, fixed-trip unrolled PV -> 512 blocks
        attn_kernel<<<dim3(T, H / 4), 256, 0, stream>>>(Qr, Kr, Vr, AO_bf);
        // O-proj partials: K=1024 split 8x128 -> 128 blocks x 8 waves
        gemm64_kernel<128><<<dim3(D / 64, NP_O, 1), 512, 0, stream>>>(
            AO_bf, D, wo, wo, wo, D, P1, D, 0, (size_t)T * D);
        rmsnorm_sum_kernel<NP_O, true><<<T, 256, 0, stream>>>(
            X, P1, ffn_norm + (size_t)l * D, Hn_bf);
        // GU partials: K=1024 split 4x256, z in {g,u} -> 352 blocks x 8 waves
        gemm64_kernel<256><<<dim3(F / 64, NP_G, 2), 512, 0, stream>>>(
            Hn_bf, D, wg, wu, wu, F, P3, GUN, F, (size_t)T * GUN);
        silu_reduce_kernel<<<dim3(F / 256, T), 256, 0, stream>>>(P3, Gact);
        // Wd partials: K=2816 split 11x256 -> 176 blocks x 8 waves
        gemm64_kernel<256><<<dim3(D / 64, NP_D, 1), 512, 0, stream>>>(
            Gact, F, wd, wd, wd, D, P2, D, 0, (size_t)T * D);
    }

    // final: xl = rmsnorm(X[127] + sum P2[c][127]) * norm_out (fp32)
    rmsnorm_sum_kernel<NP_D, false><<<1, 256, 0, stream>>>(
        X + (size_t)(T - 1) * D, P2 + (size_t)(T - 1) * D, norm_out, xl);
    logits_kernel<<<V / 4, 256, 0, stream>>>(emb, xl, out);
}